// Round 15
// baseline (565.739 us; speedup 1.0000x reference)
//
#include <hip/hip_runtime.h>

// DAG GNN recommender: N=20000 nodes, E=320000 edges, H=256, L=3, OUT=128.
// R1-R8: see history. R9/R11/R13 reverted (LDS-atomics, LN-fusion, wave/node).
// R12: GEMM BM=32 + B direct from L2. R14: light epilogue split fusion.
// R15: (a) 2-TERM GEMM for msg sections 1,2 (A=bf16-hi only; inputs already
//      bf16-limited by Hc) -> layer GEMM steps 24->16 (phase B stages chunk
//      PAIRS: waves 2,3 stage c+1-hi instead of c-lo; same slots/vmcnt);
//      (b) gather writes only hi tiles for sec1/2 (lo never read) + gacc8
//      8-edge unroll (8 loads in flight; VGPR free, occupancy grid-capped).
// Precision: sec0/head 3-term (Ah*Bh+Ah*Bl+Al*Bh); msg sections 2-term.

#define H 256
#define LAYERS 3
#define OUTD 128
#define LN_EPS 1e-5f

typedef short s16x8 __attribute__((ext_vector_type(8)));
typedef unsigned short u16x4 __attribute__((ext_vector_type(4)));
typedef unsigned short u16x8 __attribute__((ext_vector_type(8)));
typedef float f32x4 __attribute__((ext_vector_type(4)));
typedef int i32x4 __attribute__((ext_vector_type(4)));

__device__ __forceinline__ unsigned short f2bf(float f) {
  unsigned int u = __float_as_uint(f);
  u += 0x7FFFu + ((u >> 16) & 1u);     // round-to-nearest-even
  return (unsigned short)(u >> 16);
}
__device__ __forceinline__ float bf2f(unsigned short s) {
  return __uint_as_float(((unsigned int)s) << 16);
}
__device__ __forceinline__ float gelu_f(float x) {
  return 0.5f * x * (1.0f + erff(x * 0.70710678118654752440f));
}
__device__ __forceinline__ void gload16(const void* g, void* l) {
  __builtin_amdgcn_global_load_lds((const __attribute__((address_space(1))) void*)g,
                                   (__attribute__((address_space(3))) void*)l, 16, 0, 0);
}

// ---- Tile layout ----------------------------------------------------------
// Operands stored as 1KB tiles: tile t = (rb*NS + sec)*16 + c, c in 0..7 = hi
// k-chunk c (k = c*32..+31), c+8 = matching lo chunk. Within a tile:
// elem addr = (row&15)*8 + ((k>>3)&3)*128 + (k&7)  (= MFMA frag lane order).

// store hi/lo of 4 values at feature j=4l..4l+3 of `row` into tile section sec
__device__ __forceinline__ void store_split8(unsigned short* __restrict__ T, int NS, int sec,
                                             int row, int l, u16x4 hv, u16x4 lv) {
  size_t tb = ((size_t)((row >> 4) * NS + sec) << 4) + (l >> 3);
  int off = (((row & 15) + (((l >> 1) & 3) << 4)) << 3) + ((l & 1) << 2);
  *(u16x4*)(T + tb * 512 + off) = hv;
  *(u16x4*)(T + (tb + 8) * 512 + off) = lv;
}

// X [M][256] f32 -> tile-ordered hi/lo split (section 0 of NS), plus
// optional compact bf16-hi copy. One block per 16-row tile-block.
__global__ void split_tiles_kernel(const float* __restrict__ X,
                                   unsigned short* __restrict__ T, int NS,
                                   unsigned short* __restrict__ Hc, int M)
{
  const int rb = blockIdx.x;
  const int l = threadIdx.x & 63;
  const int cq = threadIdx.x >> 6;
  const int row = (rb << 4) + (l & 15);
  if (row >= M) return;
  const float* xr = X + (size_t)row * H;
#pragma unroll
  for (int p = 0; p < 2; ++p) {
    const int c = cq + (p << 2);
    const int j0 = (c << 5) + ((l >> 4) << 3);
    f32x4 v0 = *(const f32x4*)(xr + j0);
    f32x4 v1 = *(const f32x4*)(xr + j0 + 4);
    u16x8 hv, lv;
#pragma unroll
    for (int i = 0; i < 4; ++i) {
      unsigned short hb = f2bf(v0[i]); hv[i] = hb;     lv[i] = f2bf(v0[i] - bf2f(hb));
      unsigned short hc = f2bf(v1[i]); hv[4 + i] = hc; lv[4 + i] = f2bf(v1[i] - bf2f(hc));
    }
    size_t tb = ((size_t)(rb * NS) << 4);
    *(u16x8*)(T + (tb + c) * 512 + (l << 3)) = hv;
    *(u16x8*)(T + (tb + c + 8) * 512 + (l << 3)) = lv;
    if (Hc) *(u16x8*)(Hc + (size_t)row * H + j0) = hv;
  }
}

// ALL weights -> tile-ordered hi/lo in one launch. blockIdx = slot*256 + chunk.
__global__ void bext_all_kernel(const float* __restrict__ in_w,
                                const float* __restrict__ parent_w,
                                const float* __restrict__ child_w,
                                const float* __restrict__ self_w,
                                const float* __restrict__ head_w1,
                                const float* __restrict__ head_w2,
                                unsigned short* __restrict__ Bext)
{
  const int slot = blockIdx.x >> 8;
  const int chunk = blockIdx.x & 255;
  const int ncol = (slot == 11) ? OUTD : H;
  const int idx = chunk * 256 + threadIdx.x;
  if (idx >= H * ncol) return;
  const float* W =
    (slot == 0)  ? in_w :
    (slot <= 3)  ? parent_w + (size_t)(slot - 1) * H * H :
    (slot <= 6)  ? child_w  + (size_t)(slot - 4) * H * H :
    (slot <= 9)  ? self_w   + (size_t)(slot - 7) * H * H :
    (slot == 10) ? head_w1  : head_w2;
  unsigned short* Bt = Bext + (size_t)slot * H * 512;
  int k = idx / ncol;
  int n = idx - k * ncol;
  float w = W[idx];
  unsigned short hb = f2bf(w);
  unsigned short lb = f2bf(w - bf2f(hb));
  size_t base = (((size_t)(n >> 4) << 4) + (k >> 5)) * 512 +
                (((n & 15) + (((k >> 3) & 3) << 4)) << 3) + (k & 7);
  Bt[base] = hb;
  Bt[base + 8 * 512] = lb;
}

__global__ void zero2_kernel(int* __restrict__ a, int* __restrict__ b, int n) {
  int i = blockIdx.x * 256 + threadIdx.x;
  if (i < n) { a[i] = 0; b[i] = 0; }
}

__global__ void deg_kernel(const int* __restrict__ src, const int* __restrict__ dst,
                           int* __restrict__ di, int* __restrict__ dox, int E) {
  int e = blockIdx.x * 256 + threadIdx.x;
  if (e >= E) return;
  atomicAdd(&dox[src[e]], 1);
  atomicAdd(&di[dst[e]], 1);
}

// 1/deg (clamped) + zero the CSR fill cursors.
__global__ void rdeg_kernel(const int* __restrict__ di, const int* __restrict__ dox,
                            float* __restrict__ ri, float* __restrict__ ro,
                            int* __restrict__ cur_in, int* __restrict__ cur_out, int n) {
  int i = blockIdx.x * 256 + threadIdx.x;
  if (i >= n) return;
  int a = di[i];  if (a < 1) a = 1;
  int b = dox[i]; if (b < 1) b = 1;
  ri[i] = 1.0f / (float)a;
  ro[i] = 1.0f / (float)b;
  cur_in[i] = 0;
  cur_out[i] = 0;
}

// Exclusive prefix scans of both degree arrays -> rowptrs; 2 blocks of 1024.
__global__ __launch_bounds__(1024)
void scan2_kernel(const int* __restrict__ degi, const int* __restrict__ dego,
                  int* __restrict__ rp_in, int* __restrict__ rp_out, int n) {
  __shared__ int partial[1024];
  const int* deg = blockIdx.x ? dego : degi;
  int* rowptr = blockIdx.x ? rp_out : rp_in;
  const int t = threadIdx.x;
  const int chunk = (n + 1023) / 1024;
  int b = t * chunk;
  int e = b + chunk; if (e > n) e = n;
  int s = 0;
  for (int i = b; i < e; ++i) s += deg[i];
  partial[t] = s;
  __syncthreads();
  for (int off = 1; off < 1024; off <<= 1) {
    int v = (t >= off) ? partial[t - off] : 0;
    __syncthreads();
    partial[t] += v;
    __syncthreads();
  }
  int run = (t == 0) ? 0 : partial[t - 1];
  for (int i = b; i < e; ++i) { rowptr[i] = run; run += deg[i]; }
  if (t == 1023) rowptr[n] = run;
}

// CSR fill: ci_in grouped by dst holds src; ci_out grouped by src holds dst.
__global__ void fill_kernel(const int* __restrict__ src, const int* __restrict__ dst,
                            const int* __restrict__ rp_in, const int* __restrict__ rp_out,
                            int* __restrict__ cur_in, int* __restrict__ cur_out,
                            int* __restrict__ ci_in, int* __restrict__ ci_out, int E) {
  int e = blockIdx.x * 256 + threadIdx.x;
  if (e >= E) return;
  int s = src[e], d = dst[e];
  int p = atomicAdd(&cur_in[d], 1);
  ci_in[rp_in[d] + p] = s;
  int q = atomicAdd(&cur_out[s], 1);
  ci_out[rp_out[s] + q] = d;
}

// C[32 x N] = A_tiles @ B_tiles (+bias). BM=32, 4 waves = 32 rows x NF*16 cols.
// A: LDS-staged (1 gload16/wave/step). B: DIRECT from L2.
// TWOTERM (layer kernel, nsec=3): phase A = sec0, 8 steps, 3-term;
// phase B = sec1,2 as chunk PAIRS (waves 0,1 stage chunk ca-hi; waves 2,3
// stage cb=ca+1-hi into the "lo" slots), 8 steps, 2-term each chunk.
template<int NF, int GELU, int SPLIT, int TWOTERM>
__global__ __launch_bounds__(256)
void gemm_kernel(const unsigned short* __restrict__ A, int NSa,
                 const unsigned short* __restrict__ B0,
                 const unsigned short* __restrict__ B1,
                 const unsigned short* __restrict__ B2,
                 const float* __restrict__ bias, float* __restrict__ C,
                 unsigned short* __restrict__ Asp, int NSp,
                 unsigned short* __restrict__ Hc,
                 int M, int nrb, int nsec)
{
  constexpr int N = NF * 64;
  __shared__ unsigned short ldsA[2][2048];   // [buf][slot0..3] 4KB x2

  const int tid = threadIdx.x;
  const int lane = tid & 63;
  const int wn = tid >> 6;
  const int m0 = blockIdx.x << 5;
  int rbw = (blockIdx.x << 1) + (wn & 1);
  if (rbw >= nrb) rbw = nrb - 1;             // tail clamp (stores guarded)
  const int hilo = wn >> 1;

  f32x4 acc[2][NF] = {};

  auto STAGE = [&](int buf, int step) {
    int s, c;
    if (!TWOTERM || step < 8) { s = step >> 3; c = (step & 7) + (hilo << 3); }
    else { int t2 = step - 8; s = 1 + (t2 >> 2); c = ((t2 & 3) << 1) + hilo; }
    const unsigned short* pa =
        A + (((size_t)(rbw * NSa + s) << 4) + c) * 512 + (lane << 3);
    gload16(pa, &ldsA[buf][0] + (wn << 9));
  };

  auto COMPUTE = [&](int buf, int step) {
    const unsigned short* base = &ldsA[buf][0];
    s16x8 a0[2], a1[2];
#pragma unroll
    for (int f = 0; f < 2; ++f) {
      a0[f] = *(const s16x8*)(base + (f << 9) + (lane << 3));
      a1[f] = *(const s16x8*)(base + 1024 + (f << 9) + (lane << 3));
    }
    if (!TWOTERM || step < 8) {
      // 3-term: a0 = A-hi(chunk c), a1 = A-lo(chunk c)
      const int s = step >> 3;
      const int c = step & 7;
      const unsigned short* Bs = (s == 0) ? B0 : ((s == 1) ? B1 : B2);
      s16x8 bh[NF], bl[NF];
#pragma unroll
      for (int j = 0; j < NF; ++j) {
        const int g = wn * NF + j;
        bh[j] = *(const s16x8*)(Bs + ((size_t)((g << 4) + c) << 9) + (lane << 3));
        bl[j] = *(const s16x8*)(Bs + ((size_t)((g << 4) + c + 8) << 9) + (lane << 3));
      }
#pragma unroll
      for (int i = 0; i < 2; ++i)
#pragma unroll
        for (int j = 0; j < NF; ++j)
          acc[i][j] = __builtin_amdgcn_mfma_f32_16x16x32_bf16(a0[i], bh[j], acc[i][j], 0, 0, 0);
#pragma unroll
      for (int i = 0; i < 2; ++i)
#pragma unroll
        for (int j = 0; j < NF; ++j)
          acc[i][j] = __builtin_amdgcn_mfma_f32_16x16x32_bf16(a0[i], bl[j], acc[i][j], 0, 0, 0);
#pragma unroll
      for (int i = 0; i < 2; ++i)
#pragma unroll
        for (int j = 0; j < NF; ++j)
          acc[i][j] = __builtin_amdgcn_mfma_f32_16x16x32_bf16(a1[i], bh[j], acc[i][j], 0, 0, 0);
    } else {
      // 2-term pair: a0 = A-hi(chunk ca), a1 = A-hi(chunk cb)
      const int t2 = step - 8;
      const int s = 1 + (t2 >> 2);
      const int ca = (t2 & 3) << 1, cb = ca + 1;
      const unsigned short* Bs = (s == 1) ? B1 : B2;
      s16x8 bha[NF], bla[NF], bhb[NF], blb[NF];
#pragma unroll
      for (int j = 0; j < NF; ++j) {
        const int g = wn * NF + j;
        bha[j] = *(const s16x8*)(Bs + ((size_t)((g << 4) + ca) << 9) + (lane << 3));
        bla[j] = *(const s16x8*)(Bs + ((size_t)((g << 4) + ca + 8) << 9) + (lane << 3));
        bhb[j] = *(const s16x8*)(Bs + ((size_t)((g << 4) + cb) << 9) + (lane << 3));
        blb[j] = *(const s16x8*)(Bs + ((size_t)((g << 4) + cb + 8) << 9) + (lane << 3));
      }
#pragma unroll
      for (int i = 0; i < 2; ++i)
#pragma unroll
        for (int j = 0; j < NF; ++j)
          acc[i][j] = __builtin_amdgcn_mfma_f32_16x16x32_bf16(a0[i], bha[j], acc[i][j], 0, 0, 0);
#pragma unroll
      for (int i = 0; i < 2; ++i)
#pragma unroll
        for (int j = 0; j < NF; ++j)
          acc[i][j] = __builtin_amdgcn_mfma_f32_16x16x32_bf16(a0[i], bla[j], acc[i][j], 0, 0, 0);
#pragma unroll
      for (int i = 0; i < 2; ++i)
#pragma unroll
        for (int j = 0; j < NF; ++j)
          acc[i][j] = __builtin_amdgcn_mfma_f32_16x16x32_bf16(a1[i], bhb[j], acc[i][j], 0, 0, 0);
#pragma unroll
      for (int i = 0; i < 2; ++i)
#pragma unroll
        for (int j = 0; j < NF; ++j)
          acc[i][j] = __builtin_amdgcn_mfma_f32_16x16x32_bf16(a1[i], blb[j], acc[i][j], 0, 0, 0);
    }
  };

  const int nsteps = TWOTERM ? 16 : (nsec << 3);
  STAGE(0, 0);
  int cur = 0;
  for (int t = 0; t < nsteps - 1; ++t) {
    STAGE(cur ^ 1, t + 1);
    asm volatile("s_waitcnt vmcnt(1)" ::: "memory");
    __builtin_amdgcn_s_barrier();
    COMPUTE(cur, t);
    asm volatile("s_waitcnt lgkmcnt(0)" ::: "memory");   // ds_reads done before overwrite
    __builtin_amdgcn_s_barrier();
    cur ^= 1;
  }
  asm volatile("s_waitcnt vmcnt(0)" ::: "memory");
  __builtin_amdgcn_s_barrier();
  COMPUTE(cur, nsteps - 1);

  const int r0 = (lane >> 4) << 2;   // C/D: row=(lane>>4)*4+reg, col=lane&15  [m89-verified]
  const int cn = lane & 15;
#pragma unroll
  for (int j = 0; j < NF; ++j) {
    const int col = wn * (NF << 4) + (j << 4) + cn;
    const float bb = bias ? bias[col] : 0.0f;
#pragma unroll
    for (int i = 0; i < 2; ++i) {
      const int rowb = m0 + (i << 4) + r0;
#pragma unroll
      for (int r = 0; r < 4; ++r) {
        const int rr = rowb + r;
        if (rr < M) {
          float v = acc[i][j][r] + bb;
          if (GELU) v = gelu_f(v);
          if (C) C[(size_t)rr * N + col] = v;
          if (SPLIT) {
            unsigned short hb = f2bf(v);
            size_t tb = (((size_t)(rr >> 4) * NSp) << 4) + (col >> 5);
            int off = ((rr & 15) << 3) + (((col >> 3) & 3) << 7) + (col & 7);
            Asp[tb * 512 + off] = hb;
            Asp[(tb + 8) * 512 + off] = f2bf(v - bf2f(hb));
            if (Hc) Hc[((size_t)rr << 8) + col] = hb;
          }
        }
      }
    }
  }
}

// 8-feat (16B) gather accumulate; 8-edge unrolled (8 row-loads in flight).
__device__ __forceinline__ void gacc8(const int* __restrict__ ci, int beg, int end,
                                      const unsigned short* __restrict__ Hc, int foff,
                                      float* __restrict__ acc) {
  int i = beg;
  for (; i < end && (i & 3); ++i) {            // peel to int4 alignment
    u16x8 a = *(const u16x8*)(Hc + ((size_t)ci[i] << 8) + foff);
#pragma unroll
    for (int z = 0; z < 8; ++z) acc[z] += bf2f(a[z]);
  }
  for (; i + 8 <= end; i += 8) {
    i32x4 id0 = *(const i32x4*)(ci + i);
    i32x4 id1 = *(const i32x4*)(ci + i + 4);
    u16x8 a0 = *(const u16x8*)(Hc + ((size_t)id0[0] << 8) + foff);
    u16x8 a1 = *(const u16x8*)(Hc + ((size_t)id0[1] << 8) + foff);
    u16x8 a2 = *(const u16x8*)(Hc + ((size_t)id0[2] << 8) + foff);
    u16x8 a3 = *(const u16x8*)(Hc + ((size_t)id0[3] << 8) + foff);
    u16x8 a4 = *(const u16x8*)(Hc + ((size_t)id1[0] << 8) + foff);
    u16x8 a5 = *(const u16x8*)(Hc + ((size_t)id1[1] << 8) + foff);
    u16x8 a6 = *(const u16x8*)(Hc + ((size_t)id1[2] << 8) + foff);
    u16x8 a7 = *(const u16x8*)(Hc + ((size_t)id1[3] << 8) + foff);
#pragma unroll
    for (int z = 0; z < 8; ++z)
      acc[z] += ((bf2f(a0[z]) + bf2f(a1[z])) + (bf2f(a2[z]) + bf2f(a3[z]))) +
                ((bf2f(a4[z]) + bf2f(a5[z])) + (bf2f(a6[z]) + bf2f(a7[z])));
  }
  for (; i + 4 <= end; i += 4) {
    i32x4 id = *(const i32x4*)(ci + i);
    u16x8 a = *(const u16x8*)(Hc + ((size_t)id[0] << 8) + foff);
    u16x8 b = *(const u16x8*)(Hc + ((size_t)id[1] << 8) + foff);
    u16x8 c = *(const u16x8*)(Hc + ((size_t)id[2] << 8) + foff);
    u16x8 d = *(const u16x8*)(Hc + ((size_t)id[3] << 8) + foff);
#pragma unroll
    for (int z = 0; z < 8; ++z)
      acc[z] += (bf2f(a[z]) + bf2f(b[z])) + (bf2f(c[z]) + bf2f(d[z]));
  }
  for (; i < end; ++i) {
    u16x8 a = *(const u16x8*)(Hc + ((size_t)ci[i] << 8) + foff);
#pragma unroll
    for (int z = 0; z < 8; ++z) acc[z] += bf2f(a[z]);
  }
}

// Gather: block = 16 nodes x 8 threads. XCD-pinned: xcd = b&7, slice s =
// xcd>>1, rb = (b>>3)*2 + (xcd&1). Slice = 64 feats (2.5MB, L2-resident on
// 2 XCDs). R15: writes ONLY hi tiles for sections 1,2 (2-term GEMM).
__global__ __launch_bounds__(128)
void gather_kernel(
    const int* __restrict__ rp_in, const int* __restrict__ ci_in,
    const int* __restrict__ rp_out, const int* __restrict__ ci_out,
    const float* __restrict__ ri, const float* __restrict__ ro,
    const unsigned short* __restrict__ Hc, unsigned short* __restrict__ Aext,
    int M, int nrb)
{
  __shared__ unsigned short sh[2][2][512];        // [sec][cc][elems] 4KB
  const int b = blockIdx.x;
  const int xcd = b & 7;
  const int s = xcd >> 1;
  const int rb = ((b >> 3) << 1) + (xcd & 1);
  if (rb >= nrb) return;                          // whole block exits: sync-safe
  const int tid = threadIdx.x;
  const int g = tid >> 3;          // node in tile-block (0..15)
  const int t = tid & 7;           // feat octet within slice
  const int row = (rb << 4) + g;
  const int foff = (s << 6) + (t << 3);

  float hin[8] = {}, hout[8] = {};
  float wi = 0.f, wo = 0.f;
  if (row < M) {
    gacc8(ci_in,  rp_in[row],  rp_in[row + 1],  Hc, foff, hin);
    gacc8(ci_out, rp_out[row], rp_out[row + 1], Hc, foff, hout);
    wi = ri[row];
    wo = ro[row];
  }

  // stage hi-only tiles in LDS at tile-layout position
  const int cc = t >> 2;
  const int pos = (g << 3) + ((t & 3) << 7);
  u16x8 hv;
#pragma unroll
  for (int q = 0; q < 8; ++q) hv[q] = f2bf(hin[q] * wi);
  *(u16x8*)(&sh[0][cc][pos]) = hv;
#pragma unroll
  for (int q = 0; q < 8; ++q) hv[q] = f2bf(hout[q] * wo);
  *(u16x8*)(&sh[1][cc][pos]) = hv;
  __syncthreads();

  // write 4 hi tiles; 32 threads/tile, 32B/thread, 1KB contiguous per tile
  const int tp = tid >> 5;         // 0..3
  const int q = tid & 31;
  const int sec = tp >> 1, c2 = tp & 1;
  const int cg = (s << 1) + c2;    // hi k-chunk 0..7
  size_t tile = ((size_t)(rb * 3 + 1 + sec) << 4) + cg;
  unsigned short* dstp = Aext + tile * 512;
  const unsigned short* srcp = &sh[sec][c2][0];
#pragma unroll
  for (int i = 0; i < 2; ++i)
    *(u16x8*)(dstp + (i << 8) + (q << 3)) = *(const u16x8*)(srcp + (i << 8) + (q << 3));
}

// h' = LayerNorm(h + gelu(preact))*g + b; write h' fp32 + Hc + tile-split sec0.
__global__ void finalize_kernel(float* __restrict__ h, const float* __restrict__ P,
                                unsigned short* __restrict__ Aext,
                                unsigned short* __restrict__ Hc,
                                const float* __restrict__ g, const float* __restrict__ b, int M)
{
  int row = blockIdx.x * 4 + (threadIdx.x >> 6);
  if (row >= M) return;
  int l = threadIdx.x & 63;
  int j = l << 2;
  f32x4 hv = *(const f32x4*)(h + (size_t)row * H + j);
  f32x4 pv = *(const f32x4*)(P + (size_t)row * H + j);
  f32x4 t;
  float sum = 0.f, sq = 0.f;
#pragma unroll
  for (int i = 0; i < 4; ++i) {
    t[i] = hv[i] + gelu_f(pv[i]);
    sum += t[i];
    sq += t[i] * t[i];
  }
#pragma unroll
  for (int off = 1; off < 64; off <<= 1) {
    sum += __shfl_xor(sum, off, 64);
    sq  += __shfl_xor(sq, off, 64);
  }
  float mu = sum * (1.0f / H);
  float var = sq * (1.0f / H) - mu * mu;
  float rs = rsqrtf(var + LN_EPS);
  f32x4 outv;
  u16x4 hvv, lvv;
#pragma unroll
  for (int i = 0; i < 4; ++i) {
    outv[i] = (t[i] - mu) * rs * g[j + i] + b[j + i];
    unsigned short hb = f2bf(outv[i]);
    hvv[i] = hb;
    lvv[i] = f2bf(outv[i] - bf2f(hb));
  }
  *(f32x4*)(h + (size_t)row * H + j) = outv;
  *(u16x4*)(Hc + ((size_t)row << 8) + j) = hvv;
  store_split8(Aext, 3, 0, row, l, hvv, lvv);
}

extern "C" void kernel_launch(void* const* d_in, const int* in_sizes, int n_in,
                              void* d_out, int out_size, void* d_ws, size_t ws_size,
                              hipStream_t stream)
{
  const float* x        = (const float*)d_in[0];
  const int*   ei       = (const int*)d_in[1];
  const float* in_w     = (const float*)d_in[2];
  const float* in_b     = (const float*)d_in[3];
  const float* parent_w = (const float*)d_in[4];
  const float* child_w  = (const float*)d_in[5];
  const float* self_w   = (const float*)d_in[6];
  const float* self_b   = (const float*)d_in[7];
  const float* ln_g     = (const float*)d_in[8];
  const float* ln_b     = (const float*)d_in[9];
  const float* head_w1  = (const float*)d_in[10];
  const float* head_b1  = (const float*)d_in[11];
  const float* head_w2  = (const float*)d_in[12];
  const float* head_b2  = (const float*)d_in[13];

  const int M = in_sizes[0] / H;     // 20000
  const int E = in_sizes[1] / 2;     // 320000
  const int nrb = (M + 15) / 16;     // 1250
  const int* src = ei;
  const int* dst = ei + E;

  char* w = (char*)d_ws;
  auto alloc = [&](size_t bytes) { char* p = w; w += (bytes + 255) & ~(size_t)255; return p; };
  float*          h    = (float*)alloc((size_t)M * H * 4);
  float*          P    = (float*)alloc((size_t)M * H * 4);
  unsigned short* Ax   = (unsigned short*)alloc((size_t)nrb * 16 * 512 * 2);  // 1-section tiles
  unsigned short* Aext = (unsigned short*)alloc((size_t)nrb * 48 * 512 * 2);  // 3-section tiles
  unsigned short* Hc   = (unsigned short*)alloc((size_t)M * H * 2);
  unsigned short* Bext = (unsigned short*)alloc((size_t)12 * H * 512 * 2);
  int*            degi = (int*)alloc((size_t)M * 4);
  int*            dego = (int*)alloc((size_t)M * 4);
  float*          ri   = (float*)alloc((size_t)M * 4);
  float*          ro   = (float*)alloc((size_t)M * 4);
  int*            rp_in   = (int*)alloc((size_t)(M + 1) * 4);
  int*            rp_out  = (int*)alloc((size_t)(M + 1) * 4);
  int*            cur_in  = (int*)alloc((size_t)M * 4);
  int*            cur_out = (int*)alloc((size_t)M * 4);
  int*            ci_in   = (int*)alloc((size_t)E * 4);
  int*            ci_out  = (int*)alloc((size_t)E * 4);
  if ((size_t)(w - (char*)d_ws) > ws_size) return;  // insufficient scratch: fail loudly

  auto bslot = [&](int i) { return Bext + (size_t)i * H * 512; };

  // ALL weight hi/lo splits in one launch
  bext_all_kernel<<<12 * 256, 256, 0, stream>>>(in_w, parent_w, child_w, self_w,
                                                head_w1, head_w2, Bext);

  // Degrees + CSR build (layer-invariant)
  zero2_kernel<<<(M + 255) / 256, 256, 0, stream>>>(degi, dego, M);
  deg_kernel<<<(E + 255) / 256, 256, 0, stream>>>(src, dst, degi, dego, E);
  rdeg_kernel<<<(M + 255) / 256, 256, 0, stream>>>(degi, dego, ri, ro, cur_in, cur_out, M);
  scan2_kernel<<<2, 1024, 0, stream>>>(degi, dego, rp_in, rp_out, M);
  fill_kernel<<<(E + 255) / 256, 256, 0, stream>>>(src, dst, rp_in, rp_out,
                                                   cur_in, cur_out, ci_in, ci_out, E);

  const int mb32 = (M + 31) / 32;               // 625
  const int ggrid = (M + 3) / 4;
  const int xgrid = 8 * ((nrb + 1) / 2);        // XCD-pinned gather grid (5000)

  // h = x @ in_w + in_b; epilogue writes h + Aext sec0 tiles + Hc (fused split)
  split_tiles_kernel<<<nrb, 256, 0, stream>>>(x, Ax, 1, nullptr, M);
  gemm_kernel<4, 0, 1, 0><<<mb32, 256, 0, stream>>>(Ax, 1, bslot(0), nullptr, nullptr,
                                                    in_b, h, Aext, 3, Hc, M, nrb, 1);

  for (int l = 0; l < LAYERS; ++l) {
    gather_kernel<<<xgrid, 128, 0, stream>>>(rp_in, ci_in, rp_out, ci_out,
                                             ri, ro, Hc, Aext, M, nrb);
    gemm_kernel<4, 0, 0, 1><<<mb32, 256, 0, stream>>>(Aext, 3,
                                                      bslot(7 + l), bslot(1 + l), bslot(4 + l),
                                                      self_b + (size_t)l * H, P,
                                                      nullptr, 0, nullptr, M, nrb, 3);
    finalize_kernel<<<ggrid, 256, 0, stream>>>(h, P, Aext, Hc,
                                               ln_g + (size_t)l * H, ln_b + (size_t)l * H, M);
  }

  // Head: Ax = split(gelu(h@w1+b1)) fused epilogue; y = Ax@w2 + b2
  gemm_kernel<4, 1, 1, 0><<<mb32, 256, 0, stream>>>(Aext, 3, bslot(10), nullptr, nullptr,
                                                    head_b1, nullptr, Ax, 1, nullptr, M, nrb, 1);
  gemm_kernel<2, 0, 0, 0><<<mb32, 256, 0, stream>>>(Ax, 1, bslot(11), nullptr, nullptr,
                                                    head_b2, (float*)d_out, nullptr, 0, nullptr,
                                                    M, nrb, 1);
}

// Round 16
// 441.287 us; speedup vs baseline: 1.2820x; 1.2820x over previous
//
#include <hip/hip_runtime.h>

// DAG GNN recommender: N=20000 nodes, E=320000 edges, H=256, L=3, OUT=128.
// R1-R8: see history. R9/R11/R13 reverted (LDS-atomics, LN-fusion, wave/node).
// R12: GEMM BM=32 + B direct from L2. R14: light epilogue split fusion (BEST).
// R15: 2-term msg GEMM -> REGRESSED (+42us/layer: phase-B's 16 B-frag loads
//      share vmcnt with staging; blanket vmcnt(1) drains them). REVERTED.
// R16: DIRECTION-SPLIT gather: block = 2 dirs x 16 nodes x 8 octets (256 thr).
//      Per-thread serial edges halve (~32 -> ~16), waves double (fills all
//      8192 slots), dir select is wave-uniform (no divergence), no cross-lane
//      combine (R13 lesson). 8-edge-unrolled gacc8 kept.
// Precision: bf16 hi/lo split GEMM, 3 terms (Ah*Bh + Ah*Bl + Al*Bh).

#define H 256
#define LAYERS 3
#define OUTD 128
#define LN_EPS 1e-5f

typedef short s16x8 __attribute__((ext_vector_type(8)));
typedef unsigned short u16x4 __attribute__((ext_vector_type(4)));
typedef unsigned short u16x8 __attribute__((ext_vector_type(8)));
typedef float f32x4 __attribute__((ext_vector_type(4)));
typedef int i32x4 __attribute__((ext_vector_type(4)));

__device__ __forceinline__ unsigned short f2bf(float f) {
  unsigned int u = __float_as_uint(f);
  u += 0x7FFFu + ((u >> 16) & 1u);     // round-to-nearest-even
  return (unsigned short)(u >> 16);
}
__device__ __forceinline__ float bf2f(unsigned short s) {
  return __uint_as_float(((unsigned int)s) << 16);
}
__device__ __forceinline__ float gelu_f(float x) {
  return 0.5f * x * (1.0f + erff(x * 0.70710678118654752440f));
}
__device__ __forceinline__ void gload16(const void* g, void* l) {
  __builtin_amdgcn_global_load_lds((const __attribute__((address_space(1))) void*)g,
                                   (__attribute__((address_space(3))) void*)l, 16, 0, 0);
}

// ---- Tile layout ----------------------------------------------------------
// Operands stored as 1KB tiles: tile t = (rb*NS + sec)*16 + c, c in 0..7 = hi
// k-chunk c (k = c*32..+31), c+8 = matching lo chunk. Within a tile:
// elem addr = (row&15)*8 + ((k>>3)&3)*128 + (k&7)  (= MFMA frag lane order).

// store hi/lo of 4 values at feature j=4l..4l+3 of `row` into tile section sec
__device__ __forceinline__ void store_split8(unsigned short* __restrict__ T, int NS, int sec,
                                             int row, int l, u16x4 hv, u16x4 lv) {
  size_t tb = ((size_t)((row >> 4) * NS + sec) << 4) + (l >> 3);
  int off = (((row & 15) + (((l >> 1) & 3) << 4)) << 3) + ((l & 1) << 2);
  *(u16x4*)(T + tb * 512 + off) = hv;
  *(u16x4*)(T + (tb + 8) * 512 + off) = lv;
}

// X [M][256] f32 -> tile-ordered hi/lo split (section 0 of NS), plus
// optional compact bf16-hi copy. One block per 16-row tile-block.
__global__ void split_tiles_kernel(const float* __restrict__ X,
                                   unsigned short* __restrict__ T, int NS,
                                   unsigned short* __restrict__ Hc, int M)
{
  const int rb = blockIdx.x;
  const int l = threadIdx.x & 63;
  const int cq = threadIdx.x >> 6;
  const int row = (rb << 4) + (l & 15);
  if (row >= M) return;
  const float* xr = X + (size_t)row * H;
#pragma unroll
  for (int p = 0; p < 2; ++p) {
    const int c = cq + (p << 2);
    const int j0 = (c << 5) + ((l >> 4) << 3);
    f32x4 v0 = *(const f32x4*)(xr + j0);
    f32x4 v1 = *(const f32x4*)(xr + j0 + 4);
    u16x8 hv, lv;
#pragma unroll
    for (int i = 0; i < 4; ++i) {
      unsigned short hb = f2bf(v0[i]); hv[i] = hb;     lv[i] = f2bf(v0[i] - bf2f(hb));
      unsigned short hc = f2bf(v1[i]); hv[4 + i] = hc; lv[4 + i] = f2bf(v1[i] - bf2f(hc));
    }
    size_t tb = ((size_t)(rb * NS) << 4);
    *(u16x8*)(T + (tb + c) * 512 + (l << 3)) = hv;
    *(u16x8*)(T + (tb + c + 8) * 512 + (l << 3)) = lv;
    if (Hc) *(u16x8*)(Hc + (size_t)row * H + j0) = hv;
  }
}

// ALL weights -> tile-ordered hi/lo in one launch. blockIdx = slot*256 + chunk.
__global__ void bext_all_kernel(const float* __restrict__ in_w,
                                const float* __restrict__ parent_w,
                                const float* __restrict__ child_w,
                                const float* __restrict__ self_w,
                                const float* __restrict__ head_w1,
                                const float* __restrict__ head_w2,
                                unsigned short* __restrict__ Bext)
{
  const int slot = blockIdx.x >> 8;
  const int chunk = blockIdx.x & 255;
  const int ncol = (slot == 11) ? OUTD : H;
  const int idx = chunk * 256 + threadIdx.x;
  if (idx >= H * ncol) return;
  const float* W =
    (slot == 0)  ? in_w :
    (slot <= 3)  ? parent_w + (size_t)(slot - 1) * H * H :
    (slot <= 6)  ? child_w  + (size_t)(slot - 4) * H * H :
    (slot <= 9)  ? self_w   + (size_t)(slot - 7) * H * H :
    (slot == 10) ? head_w1  : head_w2;
  unsigned short* Bt = Bext + (size_t)slot * H * 512;
  int k = idx / ncol;
  int n = idx - k * ncol;
  float w = W[idx];
  unsigned short hb = f2bf(w);
  unsigned short lb = f2bf(w - bf2f(hb));
  size_t base = (((size_t)(n >> 4) << 4) + (k >> 5)) * 512 +
                (((n & 15) + (((k >> 3) & 3) << 4)) << 3) + (k & 7);
  Bt[base] = hb;
  Bt[base + 8 * 512] = lb;
}

__global__ void zero2_kernel(int* __restrict__ a, int* __restrict__ b, int n) {
  int i = blockIdx.x * 256 + threadIdx.x;
  if (i < n) { a[i] = 0; b[i] = 0; }
}

__global__ void deg_kernel(const int* __restrict__ src, const int* __restrict__ dst,
                           int* __restrict__ di, int* __restrict__ dox, int E) {
  int e = blockIdx.x * 256 + threadIdx.x;
  if (e >= E) return;
  atomicAdd(&dox[src[e]], 1);
  atomicAdd(&di[dst[e]], 1);
}

// 1/deg (clamped) + zero the CSR fill cursors.
__global__ void rdeg_kernel(const int* __restrict__ di, const int* __restrict__ dox,
                            float* __restrict__ ri, float* __restrict__ ro,
                            int* __restrict__ cur_in, int* __restrict__ cur_out, int n) {
  int i = blockIdx.x * 256 + threadIdx.x;
  if (i >= n) return;
  int a = di[i];  if (a < 1) a = 1;
  int b = dox[i]; if (b < 1) b = 1;
  ri[i] = 1.0f / (float)a;
  ro[i] = 1.0f / (float)b;
  cur_in[i] = 0;
  cur_out[i] = 0;
}

// Exclusive prefix scans of both degree arrays -> rowptrs; 2 blocks of 1024.
__global__ __launch_bounds__(1024)
void scan2_kernel(const int* __restrict__ degi, const int* __restrict__ dego,
                  int* __restrict__ rp_in, int* __restrict__ rp_out, int n) {
  __shared__ int partial[1024];
  const int* deg = blockIdx.x ? dego : degi;
  int* rowptr = blockIdx.x ? rp_out : rp_in;
  const int t = threadIdx.x;
  const int chunk = (n + 1023) / 1024;
  int b = t * chunk;
  int e = b + chunk; if (e > n) e = n;
  int s = 0;
  for (int i = b; i < e; ++i) s += deg[i];
  partial[t] = s;
  __syncthreads();
  for (int off = 1; off < 1024; off <<= 1) {
    int v = (t >= off) ? partial[t - off] : 0;
    __syncthreads();
    partial[t] += v;
    __syncthreads();
  }
  int run = (t == 0) ? 0 : partial[t - 1];
  for (int i = b; i < e; ++i) { rowptr[i] = run; run += deg[i]; }
  if (t == 1023) rowptr[n] = run;
}

// CSR fill: ci_in grouped by dst holds src; ci_out grouped by src holds dst.
__global__ void fill_kernel(const int* __restrict__ src, const int* __restrict__ dst,
                            const int* __restrict__ rp_in, const int* __restrict__ rp_out,
                            int* __restrict__ cur_in, int* __restrict__ cur_out,
                            int* __restrict__ ci_in, int* __restrict__ ci_out, int E) {
  int e = blockIdx.x * 256 + threadIdx.x;
  if (e >= E) return;
  int s = src[e], d = dst[e];
  int p = atomicAdd(&cur_in[d], 1);
  ci_in[rp_in[d] + p] = s;
  int q = atomicAdd(&cur_out[s], 1);
  ci_out[rp_out[s] + q] = d;
}

// C[32 x N] = A_tiles @ B_tiles over nsec K-sections (+bias).
// BM=32, 4 waves each = 32 rows x 64 cols (NF=4) or x32 (NF=2).
// A: LDS-staged (1 gload16/wave/step), shared. B: DIRECT from L2.
// GELU: apply gelu. SPLIT: also write bf16 hi/lo tiles (Asp, NSp) and
// optional Hc (per-element epilogue only — no cross-lane state, R11 lesson).
template<int NF, int GELU, int SPLIT>
__global__ __launch_bounds__(256)
void gemm_kernel(const unsigned short* __restrict__ A, int NSa,
                 const unsigned short* __restrict__ B0,
                 const unsigned short* __restrict__ B1,
                 const unsigned short* __restrict__ B2,
                 const float* __restrict__ bias, float* __restrict__ C,
                 unsigned short* __restrict__ Asp, int NSp,
                 unsigned short* __restrict__ Hc,
                 int M, int nrb, int nsec)
{
  constexpr int N = NF * 64;
  __shared__ unsigned short ldsA[2][2048];   // [buf][t0hi|t1hi|t0lo|t1lo] 4KB x2

  const int tid = threadIdx.x;
  const int lane = tid & 63;
  const int wn = tid >> 6;
  const int m0 = blockIdx.x << 5;
  int rbw = (blockIdx.x << 1) + (wn & 1);
  if (rbw >= nrb) rbw = nrb - 1;             // tail clamp (stores guarded)
  const int hilo = wn >> 1;                  // which half this wave stages

  f32x4 acc[2][NF] = {};

  auto STAGE = [&](int buf, int step) {
    const int s = step >> 3;
    const int c = step & 7;
    const unsigned short* pa =
        A + (((size_t)(rbw * NSa + s) << 4) + c + (hilo << 3)) * 512 + (lane << 3);
    gload16(pa, &ldsA[buf][0] + (wn << 9));
  };

  auto COMPUTE = [&](int buf, int step) {
    const int s = step >> 3;
    const int c = step & 7;
    const unsigned short* Bs = (s == 0) ? B0 : ((s == 1) ? B1 : B2);
    s16x8 bh[NF], bl[NF];
#pragma unroll
    for (int j = 0; j < NF; ++j) {           // B direct: 1KB coalesced per load
      const int g = wn * NF + j;
      bh[j] = *(const s16x8*)(Bs + ((size_t)((g << 4) + c) << 9) + (lane << 3));
      bl[j] = *(const s16x8*)(Bs + ((size_t)((g << 4) + c + 8) << 9) + (lane << 3));
    }
    const unsigned short* base = &ldsA[buf][0];
    s16x8 ah[2], al[2];
#pragma unroll
    for (int f = 0; f < 2; ++f) {
      ah[f] = *(const s16x8*)(base + (f << 9) + (lane << 3));
      al[f] = *(const s16x8*)(base + 1024 + (f << 9) + (lane << 3));
    }
#pragma unroll
    for (int i = 0; i < 2; ++i)
#pragma unroll
      for (int j = 0; j < NF; ++j)
        acc[i][j] = __builtin_amdgcn_mfma_f32_16x16x32_bf16(ah[i], bh[j], acc[i][j], 0, 0, 0);
#pragma unroll
    for (int i = 0; i < 2; ++i)
#pragma unroll
      for (int j = 0; j < NF; ++j)
        acc[i][j] = __builtin_amdgcn_mfma_f32_16x16x32_bf16(ah[i], bl[j], acc[i][j], 0, 0, 0);
#pragma unroll
    for (int i = 0; i < 2; ++i)
#pragma unroll
      for (int j = 0; j < NF; ++j)
        acc[i][j] = __builtin_amdgcn_mfma_f32_16x16x32_bf16(al[i], bh[j], acc[i][j], 0, 0, 0);
  };

  const int nsteps = nsec << 3;
  STAGE(0, 0);
  int cur = 0;
  for (int t = 0; t < nsteps - 1; ++t) {
    STAGE(cur ^ 1, t + 1);
    asm volatile("s_waitcnt vmcnt(1)" ::: "memory");
    __builtin_amdgcn_s_barrier();
    COMPUTE(cur, t);
    asm volatile("s_waitcnt lgkmcnt(0)" ::: "memory");   // ds_reads done before overwrite
    __builtin_amdgcn_s_barrier();
    cur ^= 1;
  }
  asm volatile("s_waitcnt vmcnt(0)" ::: "memory");
  __builtin_amdgcn_s_barrier();
  COMPUTE(cur, nsteps - 1);

  const int r0 = (lane >> 4) << 2;   // C/D: row=(lane>>4)*4+reg, col=lane&15  [m89-verified]
  const int cn = lane & 15;
#pragma unroll
  for (int j = 0; j < NF; ++j) {
    const int col = wn * (NF << 4) + (j << 4) + cn;
    const float bb = bias ? bias[col] : 0.0f;
#pragma unroll
    for (int i = 0; i < 2; ++i) {
      const int rowb = m0 + (i << 4) + r0;
#pragma unroll
      for (int r = 0; r < 4; ++r) {
        const int rr = rowb + r;
        if (rr < M) {
          float v = acc[i][j][r] + bb;
          if (GELU) v = gelu_f(v);
          if (C) C[(size_t)rr * N + col] = v;
          if (SPLIT) {
            unsigned short hb = f2bf(v);
            size_t tb = (((size_t)(rr >> 4) * NSp) << 4) + (col >> 5);
            int off = ((rr & 15) << 3) + (((col >> 3) & 3) << 7) + (col & 7);
            Asp[tb * 512 + off] = hb;
            Asp[(tb + 8) * 512 + off] = f2bf(v - bf2f(hb));
            if (Hc) Hc[((size_t)rr << 8) + col] = hb;
          }
        }
      }
    }
  }
}

// 8-feat (16B) gather accumulate; 8-edge unrolled (8 row-loads in flight).
__device__ __forceinline__ void gacc8(const int* __restrict__ ci, int beg, int end,
                                      const unsigned short* __restrict__ Hc, int foff,
                                      float* __restrict__ acc) {
  int i = beg;
  for (; i < end && (i & 3); ++i) {            // peel to int4 alignment
    u16x8 a = *(const u16x8*)(Hc + ((size_t)ci[i] << 8) + foff);
#pragma unroll
    for (int z = 0; z < 8; ++z) acc[z] += bf2f(a[z]);
  }
  for (; i + 8 <= end; i += 8) {
    i32x4 id0 = *(const i32x4*)(ci + i);
    i32x4 id1 = *(const i32x4*)(ci + i + 4);
    u16x8 a0 = *(const u16x8*)(Hc + ((size_t)id0[0] << 8) + foff);
    u16x8 a1 = *(const u16x8*)(Hc + ((size_t)id0[1] << 8) + foff);
    u16x8 a2 = *(const u16x8*)(Hc + ((size_t)id0[2] << 8) + foff);
    u16x8 a3 = *(const u16x8*)(Hc + ((size_t)id0[3] << 8) + foff);
    u16x8 a4 = *(const u16x8*)(Hc + ((size_t)id1[0] << 8) + foff);
    u16x8 a5 = *(const u16x8*)(Hc + ((size_t)id1[1] << 8) + foff);
    u16x8 a6 = *(const u16x8*)(Hc + ((size_t)id1[2] << 8) + foff);
    u16x8 a7 = *(const u16x8*)(Hc + ((size_t)id1[3] << 8) + foff);
#pragma unroll
    for (int z = 0; z < 8; ++z)
      acc[z] += ((bf2f(a0[z]) + bf2f(a1[z])) + (bf2f(a2[z]) + bf2f(a3[z]))) +
                ((bf2f(a4[z]) + bf2f(a5[z])) + (bf2f(a6[z]) + bf2f(a7[z])));
  }
  for (; i + 4 <= end; i += 4) {
    i32x4 id = *(const i32x4*)(ci + i);
    u16x8 a = *(const u16x8*)(Hc + ((size_t)id[0] << 8) + foff);
    u16x8 b = *(const u16x8*)(Hc + ((size_t)id[1] << 8) + foff);
    u16x8 c = *(const u16x8*)(Hc + ((size_t)id[2] << 8) + foff);
    u16x8 d = *(const u16x8*)(Hc + ((size_t)id[3] << 8) + foff);
#pragma unroll
    for (int z = 0; z < 8; ++z)
      acc[z] += (bf2f(a[z]) + bf2f(b[z])) + (bf2f(c[z]) + bf2f(d[z]));
  }
  for (; i < end; ++i) {
    u16x8 a = *(const u16x8*)(Hc + ((size_t)ci[i] << 8) + foff);
#pragma unroll
    for (int z = 0; z < 8; ++z) acc[z] += bf2f(a[z]);
  }
}

// R16 direction-split gather: block = 256 thr = 2 dirs x 16 nodes x 8 octets.
// Direction is wave-uniform (waves 0-1 = in, 2-3 = out). Per-thread serial
// work halves vs R14; no cross-lane combine. XCD-pinned: xcd = b&7,
// slice s = xcd>>1, rb = (b>>3)*2 + (xcd&1); slice = 64 feats (2.5MB,
// L2-resident on 2 XCDs). LDS-staged full hi+lo tile writes.
__global__ __launch_bounds__(256)
void gather_kernel(
    const int* __restrict__ rp_in, const int* __restrict__ ci_in,
    const int* __restrict__ rp_out, const int* __restrict__ ci_out,
    const float* __restrict__ ri, const float* __restrict__ ro,
    const unsigned short* __restrict__ Hc, unsigned short* __restrict__ Aext,
    int M, int nrb)
{
  __shared__ unsigned short sh[2][2][2][512];     // [sec][hilo][cc][elems] 8KB
  const int b = blockIdx.x;
  const int xcd = b & 7;
  const int s = xcd >> 1;
  const int rb = ((b >> 3) << 1) + (xcd & 1);
  if (rb >= nrb) return;                          // whole block exits: sync-safe
  const int tid = threadIdx.x;
  const int d = tid >> 7;          // direction (wave-uniform)
  const int g = (tid >> 3) & 15;   // node in tile-block
  const int t = tid & 7;           // feat octet within slice
  const int row = (rb << 4) + g;
  const int foff = (s << 6) + (t << 3);

  float acc[8] = {};
  float wsc = 0.f;
  if (row < M) {
    const int* __restrict__ ci = d ? ci_out : ci_in;
    const int* __restrict__ rp = d ? rp_out : rp_in;
    gacc8(ci, rp[row], rp[row + 1], Hc, foff, acc);
    wsc = d ? ro[row] : ri[row];
  }

  // split + stage in LDS at tile-layout position
  const int cc = t >> 2;
  const int pos = (g << 3) + ((t & 3) << 7);
  u16x8 hv, lv;
#pragma unroll
  for (int q = 0; q < 8; ++q) {
    float v = acc[q] * wsc;
    unsigned short hb = f2bf(v);
    hv[q] = hb; lv[q] = f2bf(v - bf2f(hb));
  }
  *(u16x8*)(&sh[d][0][cc][pos]) = hv;
  *(u16x8*)(&sh[d][1][cc][pos]) = lv;
  __syncthreads();

  // write 8 full tiles; 32 threads/tile, 32B/thread, 1KB contiguous per tile
  const int tp = tid >> 5;
  const int q = tid & 31;
  const int sec = tp >> 2, hilo = (tp >> 1) & 1, c2 = tp & 1;
  const int cg = (s << 1) + c2 + (hilo << 3);     // global k-chunk 0..15
  size_t tile = ((size_t)(rb * 3 + 1 + sec) << 4) + cg;
  unsigned short* dstp = Aext + tile * 512;
  const unsigned short* srcp = &sh[sec][hilo][c2][0];
#pragma unroll
  for (int i = 0; i < 2; ++i)
    *(u16x8*)(dstp + (i << 8) + (q << 3)) = *(const u16x8*)(srcp + (i << 8) + (q << 3));
}

// h' = LayerNorm(h + gelu(preact))*g + b; write h' fp32 + Hc + tile-split sec0.
__global__ void finalize_kernel(float* __restrict__ h, const float* __restrict__ P,
                                unsigned short* __restrict__ Aext,
                                unsigned short* __restrict__ Hc,
                                const float* __restrict__ g, const float* __restrict__ b, int M)
{
  int row = blockIdx.x * 4 + (threadIdx.x >> 6);
  if (row >= M) return;
  int l = threadIdx.x & 63;
  int j = l << 2;
  f32x4 hv = *(const f32x4*)(h + (size_t)row * H + j);
  f32x4 pv = *(const f32x4*)(P + (size_t)row * H + j);
  f32x4 t;
  float sum = 0.f, sq = 0.f;
#pragma unroll
  for (int i = 0; i < 4; ++i) {
    t[i] = hv[i] + gelu_f(pv[i]);
    sum += t[i];
    sq += t[i] * t[i];
  }
#pragma unroll
  for (int off = 1; off < 64; off <<= 1) {
    sum += __shfl_xor(sum, off, 64);
    sq  += __shfl_xor(sq, off, 64);
  }
  float mu = sum * (1.0f / H);
  float var = sq * (1.0f / H) - mu * mu;
  float rs = rsqrtf(var + LN_EPS);
  f32x4 outv;
  u16x4 hvv, lvv;
#pragma unroll
  for (int i = 0; i < 4; ++i) {
    outv[i] = (t[i] - mu) * rs * g[j + i] + b[j + i];
    unsigned short hb = f2bf(outv[i]);
    hvv[i] = hb;
    lvv[i] = f2bf(outv[i] - bf2f(hb));
  }
  *(f32x4*)(h + (size_t)row * H + j) = outv;
  *(u16x4*)(Hc + ((size_t)row << 8) + j) = hvv;
  store_split8(Aext, 3, 0, row, l, hvv, lvv);
}

extern "C" void kernel_launch(void* const* d_in, const int* in_sizes, int n_in,
                              void* d_out, int out_size, void* d_ws, size_t ws_size,
                              hipStream_t stream)
{
  const float* x        = (const float*)d_in[0];
  const int*   ei       = (const int*)d_in[1];
  const float* in_w     = (const float*)d_in[2];
  const float* in_b     = (const float*)d_in[3];
  const float* parent_w = (const float*)d_in[4];
  const float* child_w  = (const float*)d_in[5];
  const float* self_w   = (const float*)d_in[6];
  const float* self_b   = (const float*)d_in[7];
  const float* ln_g     = (const float*)d_in[8];
  const float* ln_b     = (const float*)d_in[9];
  const float* head_w1  = (const float*)d_in[10];
  const float* head_b1  = (const float*)d_in[11];
  const float* head_w2  = (const float*)d_in[12];
  const float* head_b2  = (const float*)d_in[13];

  const int M = in_sizes[0] / H;     // 20000
  const int E = in_sizes[1] / 2;     // 320000
  const int nrb = (M + 15) / 16;     // 1250
  const int* src = ei;
  const int* dst = ei + E;

  char* w = (char*)d_ws;
  auto alloc = [&](size_t bytes) { char* p = w; w += (bytes + 255) & ~(size_t)255; return p; };
  float*          h    = (float*)alloc((size_t)M * H * 4);
  float*          P    = (float*)alloc((size_t)M * H * 4);
  unsigned short* Ax   = (unsigned short*)alloc((size_t)nrb * 16 * 512 * 2);  // 1-section tiles
  unsigned short* Aext = (unsigned short*)alloc((size_t)nrb * 48 * 512 * 2);  // 3-section tiles
  unsigned short* Hc   = (unsigned short*)alloc((size_t)M * H * 2);
  unsigned short* Bext = (unsigned short*)alloc((size_t)12 * H * 512 * 2);
  int*            degi = (int*)alloc((size_t)M * 4);
  int*            dego = (int*)alloc((size_t)M * 4);
  float*          ri   = (float*)alloc((size_t)M * 4);
  float*          ro   = (float*)alloc((size_t)M * 4);
  int*            rp_in   = (int*)alloc((size_t)(M + 1) * 4);
  int*            rp_out  = (int*)alloc((size_t)(M + 1) * 4);
  int*            cur_in  = (int*)alloc((size_t)M * 4);
  int*            cur_out = (int*)alloc((size_t)M * 4);
  int*            ci_in   = (int*)alloc((size_t)E * 4);
  int*            ci_out  = (int*)alloc((size_t)E * 4);
  if ((size_t)(w - (char*)d_ws) > ws_size) return;  // insufficient scratch: fail loudly

  auto bslot = [&](int i) { return Bext + (size_t)i * H * 512; };

  // ALL weight hi/lo splits in one launch
  bext_all_kernel<<<12 * 256, 256, 0, stream>>>(in_w, parent_w, child_w, self_w,
                                                head_w1, head_w2, Bext);

  // Degrees + CSR build (layer-invariant)
  zero2_kernel<<<(M + 255) / 256, 256, 0, stream>>>(degi, dego, M);
  deg_kernel<<<(E + 255) / 256, 256, 0, stream>>>(src, dst, degi, dego, E);
  rdeg_kernel<<<(M + 255) / 256, 256, 0, stream>>>(degi, dego, ri, ro, cur_in, cur_out, M);
  scan2_kernel<<<2, 1024, 0, stream>>>(degi, dego, rp_in, rp_out, M);
  fill_kernel<<<(E + 255) / 256, 256, 0, stream>>>(src, dst, rp_in, rp_out,
                                                   cur_in, cur_out, ci_in, ci_out, E);

  const int mb32 = (M + 31) / 32;               // 625
  const int ggrid = (M + 3) / 4;
  const int xgrid = 8 * ((nrb + 1) / 2);        // XCD-pinned gather grid (5000)

  // h = x @ in_w + in_b; epilogue writes h + Aext sec0 tiles + Hc (fused split)
  split_tiles_kernel<<<nrb, 256, 0, stream>>>(x, Ax, 1, nullptr, M);
  gemm_kernel<4, 0, 1><<<mb32, 256, 0, stream>>>(Ax, 1, bslot(0), nullptr, nullptr,
                                                 in_b, h, Aext, 3, Hc, M, nrb, 1);

  for (int l = 0; l < LAYERS; ++l) {
    gather_kernel<<<xgrid, 256, 0, stream>>>(rp_in, ci_in, rp_out, ci_out,
                                             ri, ro, Hc, Aext, M, nrb);
    gemm_kernel<4, 0, 0><<<mb32, 256, 0, stream>>>(Aext, 3,
                                                   bslot(7 + l), bslot(1 + l), bslot(4 + l),
                                                   self_b + (size_t)l * H, P,
                                                   nullptr, 0, nullptr, M, nrb, 3);
    finalize_kernel<<<ggrid, 256, 0, stream>>>(h, P, Aext, Hc,
                                               ln_g + (size_t)l * H, ln_b + (size_t)l * H, M);
  }

  // Head: Ax = split(gelu(h@w1+b1)) fused epilogue; y = Ax@w2 + b2
  gemm_kernel<4, 1, 1><<<mb32, 256, 0, stream>>>(Aext, 3, bslot(10), nullptr, nullptr,
                                                 head_b1, nullptr, Ax, 1, nullptr, M, nrb, 1);
  gemm_kernel<2, 0, 0><<<mb32, 256, 0, stream>>>(Ax, 1, bslot(11), nullptr, nullptr,
                                                 head_b2, (float*)d_out, nullptr, 0, nullptr,
                                                 M, nrb, 1);
}